// Round 12
// baseline (338.607 us; speedup 1.0000x reference)
//
#include <hip/hip_runtime.h>
#include <math.h>

#define BDIM 2
#define SDIM 2048
#define HIDD 2048
#define NHH 16
#define HDD 128
#define QKDD 64
#define MTOT (BDIM*SDIM)   // 4096

constexpr float LAMBDA_INIT_F = 0.3555090675909693f;  // 0.8 - 0.6*exp(-0.3)
constexpr float EPS_F = 1e-6f;
constexpr float SCALE2_F = 0.18033688011112042f;      // (1/8) * log2(e)

typedef float f32x4 __attribute__((ext_vector_type(4)));
typedef short bf16x8 __attribute__((ext_vector_type(8)));
typedef short bf16x4 __attribute__((ext_vector_type(4)));

#define MFMA16(a, b, c) __builtin_amdgcn_mfma_f32_16x16x32_bf16((a), (b), (c), 0, 0, 0)

__device__ __forceinline__ short f2bf(float f) {
    unsigned u = __float_as_uint(f);
    u += 0x7FFFu + ((u >> 16) & 1u);   // RNE
    return (short)(u >> 16);
}
__device__ __forceinline__ unsigned pk2(float a, float b) {
    return (unsigned)(unsigned short)f2bf(a) | ((unsigned)(unsigned short)f2bf(b) << 16);
}
// HW packed f32->bf16 (RNE), lo=src0 hi=src1.
__device__ __forceinline__ unsigned cvtpk(float lo, float hi) {
    unsigned r;
    asm("v_cvt_pk_bf16_f32 %0, %1, %2" : "=v"(r) : "v"(lo), "v"(hi));
    return r;
}

__device__ __forceinline__ void gload_lds16(const void* g, void* l) {
    __builtin_amdgcn_global_load_lds(
        (const __attribute__((address_space(1))) void*)g,
        (__attribute__((address_space(3))) void*)l, 16, 0, 0);
}
__device__ __forceinline__ void waitv8() { asm volatile("s_waitcnt vmcnt(8)" ::: "memory"); }
__device__ __forceinline__ void waitv0() { asm volatile("s_waitcnt vmcnt(0)" ::: "memory"); }
__device__ __forceinline__ void waitl0() { asm volatile("s_waitcnt lgkmcnt(0)" ::: "memory"); }
#define SBAR()   __builtin_amdgcn_s_barrier()
#define SCHEDB() __builtin_amdgcn_sched_barrier(0)

// ---------------------------------------------------------------- convert ---
// Exact-span 1D grid + fused lambda (last block). Regions [q|k|v] (2^23 each)
// then [Wq|Wk|Wv|Wo] (2^22 each): 41943040/2048 = 20480 blocks + 1 lambda.
__global__ __launch_bounds__(256) void conv_all(
        const float* __restrict__ q, const float* __restrict__ k,
        const float* __restrict__ v, const float* __restrict__ Wq,
        const float* __restrict__ Wk, const float* __restrict__ Wv,
        const float* __restrict__ Wo, const float* __restrict__ lq1,
        const float* __restrict__ lk1, const float* __restrict__ lq2,
        const float* __restrict__ lk2, short* __restrict__ xdst,
        short* __restrict__ wdst, float* __restrict__ lam_out) {
    if (blockIdx.x == 20480) {
        int l = threadIdx.x;
        if (l < 64) {
            float d1 = lq1[l] * lk1[l] + lq1[l + 64] * lk1[l + 64];
            float d2 = lq2[l] * lk2[l] + lq2[l + 64] * lk2[l + 64];
#pragma unroll
            for (int o = 32; o > 0; o >>= 1) {
                d1 += __shfl_down(d1, o);
                d2 += __shfl_down(d2, o);
            }
            if (l == 0) lam_out[0] = expf(d1) - expf(d2) + LAMBDA_INIT_F;
        }
        return;
    }
    const size_t TEN_C = (size_t)1 << 23;
    const size_t WN_C  = (size_t)1 << 22;
    size_t i = ((size_t)blockIdx.x * 256 + threadIdx.x) * 8;
    const float* src;
    short* dst;
    size_t off;
    if (i < 3 * TEN_C) {
        int y = (int)(i >> 23);
        off = i & (TEN_C - 1);
        src = (y == 0) ? q : (y == 1) ? k : v;
        dst = xdst + ((size_t)y << 23);
    } else {
        size_t j = i - 3 * TEN_C;
        int y = (int)(j >> 22);
        off = j & (WN_C - 1);
        src = (y == 0) ? Wq : (y == 1) ? Wk : (y == 2) ? Wv : Wo;
        dst = wdst + ((size_t)y << 22);
    }
    float4 a = *(const float4*)&src[off];
    float4 b = *(const float4*)&src[off + 4];
    uint4 o;
    o.x = pk2(a.x, a.y); o.y = pk2(a.z, a.w);
    o.z = pk2(b.x, b.y); o.w = pk2(b.z, b.w);
    *(uint4*)&dst[off] = o;
}

// ------------------------------------------------------------ bf16 GEMM -----
// C[M,N] = X[M,K](bf16) @ W[N,K]^T(bf16). 128x128 tile, BK=64, 4 waves (2x2).
// Double-buffered LDS + counted vmcnt pipeline (round-7 validated).
#define GK 2048

__device__ __forceinline__ void gemm_mainloop(
        const short* __restrict__ X, const short* __restrict__ W,
        short* As, short* Bs, f32x4 acc[4][4],
        int bm, int bn, int w, int l, int lq, int lg, int wr, int wc) {
    const int scol = (((l & 7) ^ (l >> 3)) << 3);
    const int rsw  = (lq & 7) << 3;
    const short* aS[4]; const short* bS[4];
#pragma unroll
    for (int i = 0; i < 4; ++i) {
        const int c = w * 4 + i;
        aS[i] = X + (size_t)(bm + c * 8 + (l >> 3)) * GK + scol;
        bS[i] = W + (size_t)(bn + c * 8 + (l >> 3)) * GK + scol;
    }
    const int dOff = (w * 4) * 512;

#pragma unroll
    for (int i = 0; i < 4; ++i) {
        gload_lds16(aS[i], As + dOff + i * 512);
        gload_lds16(bS[i], Bs + dOff + i * 512);
    }
#pragma unroll
    for (int i = 0; i < 4; ++i) {
        gload_lds16(aS[i] + 64, As + 8192 + dOff + i * 512);
        gload_lds16(bS[i] + 64, Bs + 8192 + dOff + i * 512);
    }
    waitv8();
    SBAR();

    for (int t = 0; t < 30; ++t) {
        const short* Ab = As + (t & 1) * 8192;
        const short* Bb = Bs + (t & 1) * 8192;
        bf16x8 a[4][2], b[4][2];
#pragma unroll
        for (int m = 0; m < 4; ++m)
#pragma unroll
            for (int kk = 0; kk < 2; ++kk)
                a[m][kk] = *(const bf16x8*)&Ab[(wr * 64 + m * 16 + lq) * 64 + ((kk * 32 + lg * 8) ^ rsw)];
#pragma unroll
        for (int n = 0; n < 4; ++n)
#pragma unroll
            for (int kk = 0; kk < 2; ++kk)
                b[n][kk] = *(const bf16x8*)&Bb[(wc * 64 + n * 16 + lq) * 64 + ((kk * 32 + lg * 8) ^ rsw)];
        waitl0(); SCHEDB();
        SBAR();
        {
            short* Ad = As + (t & 1) * 8192 + dOff;
            short* Bd = Bs + (t & 1) * 8192 + dOff;
#pragma unroll
            for (int i = 0; i < 4; ++i) {
                gload_lds16(aS[i] + (t + 2) * 64, Ad + i * 512);
                gload_lds16(bS[i] + (t + 2) * 64, Bd + i * 512);
            }
        }
        SCHEDB();
#pragma unroll
        for (int kk = 0; kk < 2; ++kk)
#pragma unroll
            for (int m = 0; m < 4; ++m)
#pragma unroll
                for (int n = 0; n < 4; ++n)
                    acc[m][n] = MFMA16(a[m][kk], b[n][kk], acc[m][n]);
        waitv8();
        SBAR();
    }
    {
        bf16x8 a[4][2], b[4][2];
#pragma unroll
        for (int m = 0; m < 4; ++m)
#pragma unroll
            for (int kk = 0; kk < 2; ++kk)
                a[m][kk] = *(const bf16x8*)&As[(wr * 64 + m * 16 + lq) * 64 + ((kk * 32 + lg * 8) ^ rsw)];
#pragma unroll
        for (int n = 0; n < 4; ++n)
#pragma unroll
            for (int kk = 0; kk < 2; ++kk)
                b[n][kk] = *(const bf16x8*)&Bs[(wc * 64 + n * 16 + lq) * 64 + ((kk * 32 + lg * 8) ^ rsw)];
        waitl0(); SCHEDB();
        SBAR();
#pragma unroll
        for (int kk = 0; kk < 2; ++kk)
#pragma unroll
            for (int m = 0; m < 4; ++m)
#pragma unroll
                for (int n = 0; n < 4; ++n)
                    acc[m][n] = MFMA16(a[m][kk], b[n][kk], acc[m][n]);
        waitv0();
        SBAR();
    }
    {
        bf16x8 a[4][2], b[4][2];
#pragma unroll
        for (int m = 0; m < 4; ++m)
#pragma unroll
            for (int kk = 0; kk < 2; ++kk)
                a[m][kk] = *(const bf16x8*)&As[8192 + (wr * 64 + m * 16 + lq) * 64 + ((kk * 32 + lg * 8) ^ rsw)];
#pragma unroll
        for (int n = 0; n < 4; ++n)
#pragma unroll
            for (int kk = 0; kk < 2; ++kk)
                b[n][kk] = *(const bf16x8*)&Bs[8192 + (wc * 64 + n * 16 + lq) * 64 + ((kk * 32 + lg * 8) ^ rsw)];
#pragma unroll
        for (int kk = 0; kk < 2; ++kk)
#pragma unroll
            for (int m = 0; m < 4; ++m)
#pragma unroll
                for (int n = 0; n < 4; ++n)
                    acc[m][n] = MFMA16(a[m][kk], b[n][kk], acc[m][n]);
    }
}

// Batched QKV projection, 1D grid 1536 with XCD-chunked swizzle (1536%8==0).
// Within a chunk bm is fastest -> consecutive blocks share one W-panel
// (0.5 MB, L2-resident). z=0 -> Q (RoPE + SCALE2 prefold), z=1 -> K (RoPE),
// z=2 -> V (plain).
__global__ __launch_bounds__(256) void qkv_gemm(
        const short* __restrict__ Xq, const short* __restrict__ Xk, const short* __restrict__ Xv,
        const short* __restrict__ Wb, short* __restrict__ Qb, short* __restrict__ Kb,
        short* __restrict__ Vb, const float* __restrict__ cosE, const float* __restrict__ sinE) {
    __shared__ short As[2 * 128 * 64];
    __shared__ short Bs[2 * 128 * 64];
    const int tid = threadIdx.x;
    const int w = tid >> 6, l = tid & 63;
    const int lq = l & 15, lg = l >> 4;
    const int wr = w >> 1, wc = w & 1;

    const int bid = blockIdx.x;
    const int swz = (bid & 7) * 192 + (bid >> 3);
    const int z   = swz >> 9;
    const int rr  = swz & 511;
    const int bn  = (rr >> 5) * 128;
    const int bm  = (rr & 31) * 128;

    const short* X = (z == 0) ? Xq : (z == 1) ? Xk : Xv;
    const short* W = Wb + (size_t)z * HIDD * HIDD;
    short* Cb      = (z == 0) ? Qb : (z == 1) ? Kb : Vb;

    f32x4 acc[4][4] = {};
    gemm_mainloop(X, W, As, Bs, acc, bm, bn, w, l, lq, lg, wr, wc);

    const bool dorope = (z < 2);
    const float post = (z == 0) ? SCALE2_F : 1.0f;   // prefold score scale into Q
#pragma unroll
    for (int m = 0; m < 4; ++m)
#pragma unroll
        for (int n = 0; n < 4; ++n) {
            const int row0 = bm + wr * 64 + m * 16 + lg * 4;
            const int col  = bn + wc * 64 + n * 16 + lq;
#pragma unroll
            for (int r = 0; r < 4; ++r) {
                float vv = acc[m][n][r];
                if (dorope) {
                    const int s  = (row0 + r) & (SDIM - 1);
                    const int c6 = col & 63;
                    const float cv = cosE[s * HDD + c6];
                    const float sv = sinE[s * HDD + c6];
                    const float p = __shfl_xor(vv, 1);
                    vv = (col & 1) ? vv * cv + p * sv : vv * cv - p * sv;
                    vv *= post;
                }
                Cb[(size_t)(row0 + r) * HIDD + col] = f2bf(vv);
            }
        }
}

// Output projection: fp32 C, 1D grid 512 with XCD-chunked swizzle.
__global__ __launch_bounds__(256) void o_gemm(const short* __restrict__ Ab,
                                              const short* __restrict__ Bb,
                                              float* __restrict__ C) {
    __shared__ short As[2 * 128 * 64];
    __shared__ short Bs[2 * 128 * 64];
    const int tid = threadIdx.x;
    const int w = tid >> 6, l = tid & 63;
    const int lq = l & 15, lg = l >> 4;
    const int wr = w >> 1, wc = w & 1;

    const int bid = blockIdx.x;
    const int swz = (bid & 7) * 64 + (bid >> 3);
    const int bn  = (swz >> 5) * 128;
    const int bm  = (swz & 31) * 128;

    f32x4 acc[4][4] = {};
    gemm_mainloop(Ab, Bb, As, Bs, acc, bm, bn, w, l, lq, lg, wr, wc);

#pragma unroll
    for (int m = 0; m < 4; ++m)
#pragma unroll
        for (int n = 0; n < 4; ++n) {
            const int row0 = bm + wr * 64 + m * 16 + lg * 4;
            const int col  = bn + wc * 64 + n * 16 + lq;
#pragma unroll
            for (int r = 0; r < 4; ++r)
                C[(size_t)(row0 + r) * HIDD + col] = acc[m][n][r];
        }
}

// ------------------------------------------------- MFMA differential flash --
// Round-11 structure + pre-scaled Q (no per-score mul) + permuted VT layout
// for b128 PV reads. Key position p(k) = (k>>5)*32 + ((k>>2)&3)*8 +
// ((k>>4)&1)*4 + (k&3): pa[0] slots <-> vrow[lg*8..+7], pa[1] <-> vrow[32+lg*8].
#define KVB 64

__device__ __forceinline__ bf16x8 pack_pa(const float p0[4], const float p1[4]) {
    union { unsigned u[4]; bf16x8 v; } r;
    r.u[0] = cvtpk(p0[0], p0[1]);
    r.u[1] = cvtpk(p0[2], p0[3]);
    r.u[2] = cvtpk(p1[0], p1[1]);
    r.u[3] = cvtpk(p1[2], p1[3]);
    return r.v;
}

__device__ __forceinline__ void softmax_step(
        f32x4 sc[4], float& M, float& L, f32x4 O[8], bf16x8 pa[2],
        int t0, int qg, int lg, bool domask) {
    // scores arrive pre-scaled (Q carried 1/8*log2e); mask only on diag tiles
    if (domask) {
#pragma unroll
        for (int sub = 0; sub < 4; ++sub)
#pragma unroll
            for (int r = 0; r < 4; ++r) {
                int key = t0 + sub * 16 + lg * 4 + r;
                if (key > qg) sc[sub][r] = -1e30f;
            }
    }
    float mx = -1e30f;
#pragma unroll
    for (int sub = 0; sub < 4; ++sub) {
        float a01 = fmaxf(sc[sub][0], sc[sub][1]);
        float a23 = fmaxf(sc[sub][2], sc[sub][3]);
        mx = fmaxf(mx, fmaxf(a01, a23));
    }
    mx = fmaxf(mx, __shfl_xor(mx, 16));
    mx = fmaxf(mx, __shfl_xor(mx, 32));
    if (__ballot(mx > M + 8.f)) {           // defer-max: P bounded by 2^8
        const float Mn = fmaxf(M, mx);
        const float a = __builtin_amdgcn_exp2f(M - Mn);
        M = Mn;
        L *= a;
        float ar[4];
#pragma unroll
        for (int r = 0; r < 4; ++r) ar[r] = __shfl(a, lg * 4 + r);
#pragma unroll
        for (int d = 0; d < 8; ++d) {
            O[d][0] *= ar[0]; O[d][1] *= ar[1]; O[d][2] *= ar[2]; O[d][3] *= ar[3];
        }
    }
    float p[4][4];
    float ps = 0.f;
#pragma unroll
    for (int sub = 0; sub < 4; ++sub) {
#pragma unroll
        for (int r = 0; r < 4; ++r) p[sub][r] = __builtin_amdgcn_exp2f(sc[sub][r] - M);
        ps += (p[sub][0] + p[sub][1]) + (p[sub][2] + p[sub][3]);
    }
    ps += __shfl_xor(ps, 16);
    ps += __shfl_xor(ps, 32);
    L += ps;
    pa[0] = pack_pa(p[0], p[1]);
    pa[1] = pack_pa(p[2], p[3]);
}

__global__ __launch_bounds__(256, 2) void flash_mfma(
        const short* __restrict__ Qb, const short* __restrict__ Kb,
        const short* __restrict__ Vb, const float* __restrict__ gnw,
        const float* __restrict__ lam_p, short* __restrict__ Hob) {
    __shared__ short Ksh[KVB * 128];   // row-major, 16B-group xor-swizzled
    __shared__ short VT[HDD * 72];     // VT[d][p(key)], row stride 72 shorts

    const int tid = threadIdx.x;
    const int w  = tid >> 6;
    const int l  = tid & 63;
    const int lq = l & 15;
    const int lg = l >> 4;

    const int blk = blockIdx.x;
    const int bh  = blk & 31;
    const int g   = blk >> 5;
    const int r4  = g >> 3, gc = g & 7;
    const int bx  = (r4 == 0) ? 31 - gc : (r4 == 1) ? gc
                  : (r4 == 2) ? 23 - gc : 8 + gc;    // per-CU balanced (66 tiles)
    const int b = bh >> 4, h = bh & 15;
    const int s0 = bx * 64;
    const float lam = lam_p[0];

    const int qg = s0 + w * 16 + lq;
    const short* qrow = Qb + ((size_t)(b * SDIM + qg)) * HIDD + h * HDD;
    bf16x8 qf[2][2];
#pragma unroll
    for (int br = 0; br < 2; ++br)
#pragma unroll
        for (int ks = 0; ks < 2; ++ks)
            qf[br][ks] = *(const bf16x8*)(qrow + br * 64 + ks * 32 + lg * 8);

    int kkey[4], kcol[4];
#pragma unroll
    for (int i = 0; i < 4; ++i) {
        kkey[i] = w * 16 + i * 4 + lg;
        kcol[i] = (lq * 8) ^ ((kkey[i] & 7) << 3);
    }
    const int kp = tid & 31, dq = tid >> 5;
    // permuted write position for key pair {2kp, 2kp+1} (p(2kp) even, p+1 adj)
    const int k0v = 2 * kp;
    const int vp  = ((k0v >> 5) << 5) + (((k0v >> 2) & 3) << 3)
                  + (((k0v >> 4) & 1) << 2) + (k0v & 3);

    const short* Kbase = Kb + ((size_t)(b * SDIM)) * HIDD + h * HDD;
    const short* Vbase = Vb + ((size_t)(b * SDIM)) * HIDD + h * HDD;

    float M1 = -1e30f, M2 = -1e30f, L1 = 0.f, L2 = 0.f;
    f32x4 O1[8] = {}; f32x4 O2[8] = {};

    const int ntmax = bx + 1;
    const int qmin = s0 + w * 16;

    for (int t = 0; t < ntmax; ++t) {
        const size_t trow = (size_t)t * KVB * HIDD;
        __syncthreads();
#pragma unroll
        for (int i = 0; i < 4; ++i)
            gload_lds16(Kbase + trow + (size_t)kkey[i] * HIDD + kcol[i],
                        &Ksh[w * 2048 + i * 512]);
        {
            const short* v0 = Vbase + trow + (size_t)k0v * HIDD + dq * 16;
            const short* v1 = v0 + HIDD;
            bf16x8 v00 = *(const bf16x8*)v0;
            bf16x8 v01 = *(const bf16x8*)(v0 + 8);
            bf16x8 v10 = *(const bf16x8*)v1;
            bf16x8 v11 = *(const bf16x8*)(v1 + 8);
#pragma unroll
            for (int j = 0; j < 8; ++j) {
                unsigned ua = (unsigned)(unsigned short)v00[j] |
                              ((unsigned)(unsigned short)v10[j] << 16);
                *(unsigned*)&VT[(dq * 16 + j) * 72 + vp] = ua;
                unsigned ub = (unsigned)(unsigned short)v01[j] |
                              ((unsigned)(unsigned short)v11[j] << 16);
                *(unsigned*)&VT[(dq * 16 + 8 + j) * 72 + vp] = ub;
            }
        }
        __syncthreads();

        f32x4 sc1[4] = {}; f32x4 sc2[4] = {};
        const int rsw = (lq & 7) << 3;
        __builtin_amdgcn_s_setprio(1);
#pragma unroll
        for (int sub = 0; sub < 4; ++sub) {
            const int rbase = (sub * 16 + lq) * 128;
            bf16x8 k00 = *(const bf16x8*)&Ksh[rbase + ((lg * 8) ^ rsw)];
            bf16x8 k01 = *(const bf16x8*)&Ksh[rbase + ((32 + lg * 8) ^ rsw)];
            bf16x8 k10 = *(const bf16x8*)&Ksh[rbase + ((64 + lg * 8) ^ rsw)];
            bf16x8 k11 = *(const bf16x8*)&Ksh[rbase + ((96 + lg * 8) ^ rsw)];
            sc1[sub] = MFMA16(k00, qf[0][0], sc1[sub]);
            sc1[sub] = MFMA16(k01, qf[0][1], sc1[sub]);
            sc2[sub] = MFMA16(k10, qf[1][0], sc2[sub]);
            sc2[sub] = MFMA16(k11, qf[1][1], sc2[sub]);
        }
        __builtin_amdgcn_s_setprio(0);
        const int t0 = t * KVB;
        const bool domask = (t0 + KVB - 1 > qmin);
        bf16x8 pa1[2], pa2[2];
        softmax_step(sc1, M1, L1, O1, pa1, t0, qg, lg, domask);
        softmax_step(sc2, M2, L2, O2, pa2, t0, qg, lg, domask);

        __builtin_amdgcn_s_setprio(1);
#pragma unroll
        for (int d0 = 0; d0 < 8; ++d0) {
            const short* vrow = &VT[(d0 * 16 + lq) * 72];
            bf16x8 vb0 = *(const bf16x8*)&vrow[lg * 8];
            bf16x8 vb1 = *(const bf16x8*)&vrow[32 + lg * 8];
            O1[d0] = MFMA16(pa1[0], vb0, O1[d0]);
            O1[d0] = MFMA16(pa1[1], vb1, O1[d0]);
            O2[d0] = MFMA16(pa2[0], vb0, O2[d0]);
            O2[d0] = MFMA16(pa2[1], vb1, O2[d0]);
        }
        __builtin_amdgcn_s_setprio(0);
    }

    const float inv1 = 1.f / L1;
    const float inv2 = lam / L2;
    float i1[4], i2[4];
#pragma unroll
    for (int r = 0; r < 4; ++r) {
        i1[r] = __shfl(inv1, lg * 4 + r);
        i2[r] = __shfl(inv2, lg * 4 + r);
    }
    float gn[8];
#pragma unroll
    for (int d = 0; d < 8; ++d) gn[d] = gnw[d * 16 + lq];
    float od[8][4];
    float ss[4] = {0.f, 0.f, 0.f, 0.f};
#pragma unroll
    for (int d = 0; d < 8; ++d)
#pragma unroll
        for (int r = 0; r < 4; ++r) {
            float o = O1[d][r] * i1[r] - O2[d][r] * i2[r];
            od[d][r] = o;
            ss[r] += o * o;
        }
#pragma unroll
    for (int r = 0; r < 4; ++r) {
        ss[r] += __shfl_xor(ss[r], 1);
        ss[r] += __shfl_xor(ss[r], 2);
        ss[r] += __shfl_xor(ss[r], 4);
        ss[r] += __shfl_xor(ss[r], 8);
    }
#pragma unroll
    for (int r = 0; r < 4; ++r) {
        const float scal = rsqrtf(ss[r] * (1.0f / HDD) + EPS_F) * (1.0f - LAMBDA_INIT_F);
        const size_t orow = ((size_t)(b * SDIM + s0 + w * 16 + lg * 4 + r)) * HIDD + h * HDD;
#pragma unroll
        for (int d = 0; d < 8; ++d)
            Hob[orow + d * 16 + lq] = f2bf(od[d][r] * scal * gn[d]);
    }
}

// ----------------------------------------------------------------- launch ---
extern "C" void kernel_launch(void* const* d_in, const int* in_sizes, int n_in,
                              void* d_out, int out_size, void* d_ws, size_t ws_size,
                              hipStream_t stream) {
    const float* q   = (const float*)d_in[0];
    const float* k   = (const float*)d_in[1];
    const float* v   = (const float*)d_in[2];
    const float* Wq  = (const float*)d_in[3];
    const float* Wk  = (const float*)d_in[4];
    const float* Wv  = (const float*)d_in[5];
    const float* Wo  = (const float*)d_in[6];
    const float* lq1 = (const float*)d_in[7];
    const float* lk1 = (const float*)d_in[8];
    const float* lq2 = (const float*)d_in[9];
    const float* lk2 = (const float*)d_in[10];
    const float* gnw = (const float*)d_in[11];
    const float* cosE = (const float*)d_in[12];
    const float* sinE = (const float*)d_in[13];
    float* out = (float*)d_out;

    const size_t TEN = (size_t)BDIM * SDIM * HIDD;  // 8388608 = 2^23
    const int   WN  = HIDD * HIDD;                  // 4194304 = 2^22

    short* wsS = (short*)d_ws;
    short* Qb   = wsS;
    short* Kb   = wsS + TEN;
    short* Vb   = wsS + 2 * TEN;
    short* xqkv = wsS + 3 * TEN;
    short* wb4  = wsS + 6 * TEN;
    float* lamp = (float*)(wsS + 6 * TEN + (size_t)4 * WN);
    short* Hob  = xqkv;

    conv_all<<<20481, 256, 0, stream>>>(q, k, v, Wq, Wk, Wv, Wo,
                                        lq1, lk1, lq2, lk2, xqkv, wb4, lamp);

    qkv_gemm<<<1536, 256, 0, stream>>>(xqkv, xqkv + TEN, xqkv + 2 * TEN, wb4,
                                       Qb, Kb, Vb, cosE, sinE);

    flash_mfma<<<(SDIM / 64) * BDIM * NHH, 256, 0, stream>>>(Qb, Kb, Vb, gnw, lamp, Hob);

    o_gemm<<<512, 256, 0, stream>>>(Hob, wb4 + (size_t)3 * WN, out);
}

// Round 13
// 327.449 us; speedup vs baseline: 1.0341x; 1.0341x over previous
//
#include <hip/hip_runtime.h>
#include <math.h>

#define BDIM 2
#define SDIM 2048
#define HIDD 2048
#define NHH 16
#define HDD 128
#define QKDD 64
#define MTOT (BDIM*SDIM)   // 4096

constexpr float LAMBDA_INIT_F = 0.3555090675909693f;  // 0.8 - 0.6*exp(-0.3)
constexpr float EPS_F = 1e-6f;
constexpr float SCALE2_F = 0.18033688011112042f;      // (1/8) * log2(e)

typedef float f32x4 __attribute__((ext_vector_type(4)));
typedef short bf16x8 __attribute__((ext_vector_type(8)));
typedef short bf16x4 __attribute__((ext_vector_type(4)));

#define MFMA16(a, b, c) __builtin_amdgcn_mfma_f32_16x16x32_bf16((a), (b), (c), 0, 0, 0)

__device__ __forceinline__ short f2bf(float f) {
    unsigned u = __float_as_uint(f);
    u += 0x7FFFu + ((u >> 16) & 1u);   // RNE
    return (short)(u >> 16);
}
__device__ __forceinline__ unsigned pk2(float a, float b) {
    return (unsigned)(unsigned short)f2bf(a) | ((unsigned)(unsigned short)f2bf(b) << 16);
}
// HW packed f32->bf16 (RNE), lo=src0 hi=src1.
__device__ __forceinline__ unsigned cvtpk(float lo, float hi) {
    unsigned r;
    asm("v_cvt_pk_bf16_f32 %0, %1, %2" : "=v"(r) : "v"(lo), "v"(hi));
    return r;
}

__device__ __forceinline__ void gload_lds16(const void* g, void* l) {
    __builtin_amdgcn_global_load_lds(
        (const __attribute__((address_space(1))) void*)g,
        (__attribute__((address_space(3))) void*)l, 16, 0, 0);
}
__device__ __forceinline__ void waitv8() { asm volatile("s_waitcnt vmcnt(8)" ::: "memory"); }
__device__ __forceinline__ void waitv0() { asm volatile("s_waitcnt vmcnt(0)" ::: "memory"); }
__device__ __forceinline__ void waitl0() { asm volatile("s_waitcnt lgkmcnt(0)" ::: "memory"); }
#define SBAR()   __builtin_amdgcn_s_barrier()
#define SCHEDB() __builtin_amdgcn_sched_barrier(0)

// ---------------------------------------------------------------- convert ---
// Exact-span 1D grid + fused lambda (last block). Regions [q|k|v] (2^23 each)
// then [Wq|Wk|Wv|Wo] (2^22 each): 41943040/2048 = 20480 blocks + 1 lambda.
__global__ __launch_bounds__(256) void conv_all(
        const float* __restrict__ q, const float* __restrict__ k,
        const float* __restrict__ v, const float* __restrict__ Wq,
        const float* __restrict__ Wk, const float* __restrict__ Wv,
        const float* __restrict__ Wo, const float* __restrict__ lq1,
        const float* __restrict__ lk1, const float* __restrict__ lq2,
        const float* __restrict__ lk2, short* __restrict__ xdst,
        short* __restrict__ wdst, float* __restrict__ lam_out) {
    if (blockIdx.x == 20480) {
        int l = threadIdx.x;
        if (l < 64) {
            float d1 = lq1[l] * lk1[l] + lq1[l + 64] * lk1[l + 64];
            float d2 = lq2[l] * lk2[l] + lq2[l + 64] * lk2[l + 64];
#pragma unroll
            for (int o = 32; o > 0; o >>= 1) {
                d1 += __shfl_down(d1, o);
                d2 += __shfl_down(d2, o);
            }
            if (l == 0) lam_out[0] = expf(d1) - expf(d2) + LAMBDA_INIT_F;
        }
        return;
    }
    const size_t TEN_C = (size_t)1 << 23;
    const size_t WN_C  = (size_t)1 << 22;
    size_t i = ((size_t)blockIdx.x * 256 + threadIdx.x) * 8;
    const float* src;
    short* dst;
    size_t off;
    if (i < 3 * TEN_C) {
        int y = (int)(i >> 23);
        off = i & (TEN_C - 1);
        src = (y == 0) ? q : (y == 1) ? k : v;
        dst = xdst + ((size_t)y << 23);
    } else {
        size_t j = i - 3 * TEN_C;
        int y = (int)(j >> 22);
        off = j & (WN_C - 1);
        src = (y == 0) ? Wq : (y == 1) ? Wk : (y == 2) ? Wv : Wo;
        dst = wdst + ((size_t)y << 22);
    }
    float4 a = *(const float4*)&src[off];
    float4 b = *(const float4*)&src[off + 4];
    uint4 o;
    o.x = pk2(a.x, a.y); o.y = pk2(a.z, a.w);
    o.z = pk2(b.x, b.y); o.w = pk2(b.z, b.w);
    *(uint4*)&dst[off] = o;
}

// ------------------------------------------------------------ bf16 GEMM -----
// C[M,N] = X[M,K](bf16) @ W[N,K]^T(bf16). 128x128 tile, BK=64, 4 waves (2x2).
// Double-buffered LDS + counted vmcnt pipeline (round-7 validated).
#define GK 2048

__device__ __forceinline__ void gemm_mainloop(
        const short* __restrict__ X, const short* __restrict__ W,
        short* As, short* Bs, f32x4 acc[4][4],
        int bm, int bn, int w, int l, int lq, int lg, int wr, int wc) {
    const int scol = (((l & 7) ^ (l >> 3)) << 3);
    const int rsw  = (lq & 7) << 3;
    const short* aS[4]; const short* bS[4];
#pragma unroll
    for (int i = 0; i < 4; ++i) {
        const int c = w * 4 + i;
        aS[i] = X + (size_t)(bm + c * 8 + (l >> 3)) * GK + scol;
        bS[i] = W + (size_t)(bn + c * 8 + (l >> 3)) * GK + scol;
    }
    const int dOff = (w * 4) * 512;

#pragma unroll
    for (int i = 0; i < 4; ++i) {
        gload_lds16(aS[i], As + dOff + i * 512);
        gload_lds16(bS[i], Bs + dOff + i * 512);
    }
#pragma unroll
    for (int i = 0; i < 4; ++i) {
        gload_lds16(aS[i] + 64, As + 8192 + dOff + i * 512);
        gload_lds16(bS[i] + 64, Bs + 8192 + dOff + i * 512);
    }
    waitv8();
    SBAR();

    for (int t = 0; t < 30; ++t) {
        const short* Ab = As + (t & 1) * 8192;
        const short* Bb = Bs + (t & 1) * 8192;
        bf16x8 a[4][2], b[4][2];
#pragma unroll
        for (int m = 0; m < 4; ++m)
#pragma unroll
            for (int kk = 0; kk < 2; ++kk)
                a[m][kk] = *(const bf16x8*)&Ab[(wr * 64 + m * 16 + lq) * 64 + ((kk * 32 + lg * 8) ^ rsw)];
#pragma unroll
        for (int n = 0; n < 4; ++n)
#pragma unroll
            for (int kk = 0; kk < 2; ++kk)
                b[n][kk] = *(const bf16x8*)&Bb[(wc * 64 + n * 16 + lq) * 64 + ((kk * 32 + lg * 8) ^ rsw)];
        waitl0(); SCHEDB();
        SBAR();
        {
            short* Ad = As + (t & 1) * 8192 + dOff;
            short* Bd = Bs + (t & 1) * 8192 + dOff;
#pragma unroll
            for (int i = 0; i < 4; ++i) {
                gload_lds16(aS[i] + (t + 2) * 64, Ad + i * 512);
                gload_lds16(bS[i] + (t + 2) * 64, Bd + i * 512);
            }
        }
        SCHEDB();
#pragma unroll
        for (int kk = 0; kk < 2; ++kk)
#pragma unroll
            for (int m = 0; m < 4; ++m)
#pragma unroll
                for (int n = 0; n < 4; ++n)
                    acc[m][n] = MFMA16(a[m][kk], b[n][kk], acc[m][n]);
        waitv8();
        SBAR();
    }
    {
        bf16x8 a[4][2], b[4][2];
#pragma unroll
        for (int m = 0; m < 4; ++m)
#pragma unroll
            for (int kk = 0; kk < 2; ++kk)
                a[m][kk] = *(const bf16x8*)&As[(wr * 64 + m * 16 + lq) * 64 + ((kk * 32 + lg * 8) ^ rsw)];
#pragma unroll
        for (int n = 0; n < 4; ++n)
#pragma unroll
            for (int kk = 0; kk < 2; ++kk)
                b[n][kk] = *(const bf16x8*)&Bs[(wc * 64 + n * 16 + lq) * 64 + ((kk * 32 + lg * 8) ^ rsw)];
        waitl0(); SCHEDB();
        SBAR();
#pragma unroll
        for (int kk = 0; kk < 2; ++kk)
#pragma unroll
            for (int m = 0; m < 4; ++m)
#pragma unroll
                for (int n = 0; n < 4; ++n)
                    acc[m][n] = MFMA16(a[m][kk], b[n][kk], acc[m][n]);
        waitv0();
        SBAR();
    }
    {
        bf16x8 a[4][2], b[4][2];
#pragma unroll
        for (int m = 0; m < 4; ++m)
#pragma unroll
            for (int kk = 0; kk < 2; ++kk)
                a[m][kk] = *(const bf16x8*)&As[8192 + (wr * 64 + m * 16 + lq) * 64 + ((kk * 32 + lg * 8) ^ rsw)];
#pragma unroll
        for (int n = 0; n < 4; ++n)
#pragma unroll
            for (int kk = 0; kk < 2; ++kk)
                b[n][kk] = *(const bf16x8*)&Bs[8192 + (wc * 64 + n * 16 + lq) * 64 + ((kk * 32 + lg * 8) ^ rsw)];
#pragma unroll
        for (int kk = 0; kk < 2; ++kk)
#pragma unroll
            for (int m = 0; m < 4; ++m)
#pragma unroll
                for (int n = 0; n < 4; ++n)
                    acc[m][n] = MFMA16(a[m][kk], b[n][kk], acc[m][n]);
    }
}

// Batched QKV projection (natural 3D grid — round-11 validated).
// z=0 -> Q (RoPE + SCALE2 prefold), z=1 -> K (RoPE), z=2 -> V (plain).
__global__ __launch_bounds__(256) void qkv_gemm(
        const short* __restrict__ Xq, const short* __restrict__ Xk, const short* __restrict__ Xv,
        const short* __restrict__ Wb, short* __restrict__ Qb, short* __restrict__ Kb,
        short* __restrict__ Vb, const float* __restrict__ cosE, const float* __restrict__ sinE) {
    __shared__ short As[2 * 128 * 64];
    __shared__ short Bs[2 * 128 * 64];
    const int tid = threadIdx.x;
    const int w = tid >> 6, l = tid & 63;
    const int lq = l & 15, lg = l >> 4;
    const int wr = w >> 1, wc = w & 1;
    const int bm = blockIdx.y * 128;
    const int bn = blockIdx.x * 128;
    const int z  = blockIdx.z;

    const short* X = (z == 0) ? Xq : (z == 1) ? Xk : Xv;
    const short* W = Wb + (size_t)z * HIDD * HIDD;
    short* Cb      = (z == 0) ? Qb : (z == 1) ? Kb : Vb;

    f32x4 acc[4][4] = {};
    gemm_mainloop(X, W, As, Bs, acc, bm, bn, w, l, lq, lg, wr, wc);

    const bool dorope = (z < 2);
    const float post = (z == 0) ? SCALE2_F : 1.0f;   // prefold score scale into Q
#pragma unroll
    for (int m = 0; m < 4; ++m)
#pragma unroll
        for (int n = 0; n < 4; ++n) {
            const int row0 = bm + wr * 64 + m * 16 + lg * 4;
            const int col  = bn + wc * 64 + n * 16 + lq;
#pragma unroll
            for (int r = 0; r < 4; ++r) {
                float vv = acc[m][n][r];
                if (dorope) {
                    const int s  = (row0 + r) & (SDIM - 1);
                    const int c6 = col & 63;
                    const float cv = cosE[s * HDD + c6];
                    const float sv = sinE[s * HDD + c6];
                    const float p = __shfl_xor(vv, 1);
                    vv = (col & 1) ? vv * cv + p * sv : vv * cv - p * sv;
                    vv *= post;
                }
                Cb[(size_t)(row0 + r) * HIDD + col] = f2bf(vv);
            }
        }
}

// Output projection: fp32 C (natural 2D grid — round-11 validated).
__global__ __launch_bounds__(256) void o_gemm(const short* __restrict__ Ab,
                                              const short* __restrict__ Bb,
                                              float* __restrict__ C) {
    __shared__ short As[2 * 128 * 64];
    __shared__ short Bs[2 * 128 * 64];
    const int tid = threadIdx.x;
    const int w = tid >> 6, l = tid & 63;
    const int lq = l & 15, lg = l >> 4;
    const int wr = w >> 1, wc = w & 1;
    const int bm = blockIdx.y * 128;
    const int bn = blockIdx.x * 128;

    f32x4 acc[4][4] = {};
    gemm_mainloop(Ab, Bb, As, Bs, acc, bm, bn, w, l, lq, lg, wr, wc);

#pragma unroll
    for (int m = 0; m < 4; ++m)
#pragma unroll
        for (int n = 0; n < 4; ++n) {
            const int row0 = bm + wr * 64 + m * 16 + lg * 4;
            const int col  = bn + wc * 64 + n * 16 + lq;
#pragma unroll
            for (int r = 0; r < 4; ++r)
                C[(size_t)(row0 + r) * HIDD + col] = acc[m][n][r];
        }
}

// ------------------------------------------------- MFMA differential flash --
// Round-11 validated structure (split bf16x4 VT reads, stride-72, balanced bx,
// cvt_pk P-pack) with pre-scaled Q (no per-score mul in softmax).
#define KVB 64

__device__ __forceinline__ bf16x8 pack_pa(const float p0[4], const float p1[4]) {
    union { unsigned u[4]; bf16x8 v; } r;
    r.u[0] = cvtpk(p0[0], p0[1]);
    r.u[1] = cvtpk(p0[2], p0[3]);
    r.u[2] = cvtpk(p1[0], p1[1]);
    r.u[3] = cvtpk(p1[2], p1[3]);
    return r.v;
}

__device__ __forceinline__ void softmax_step(
        f32x4 sc[4], float& M, float& L, f32x4 O[8], bf16x8 pa[2],
        int t0, int qg, int lg, bool domask) {
    // scores arrive pre-scaled (Q carried 1/8*log2e); mask only on diag tiles
    if (domask) {
#pragma unroll
        for (int sub = 0; sub < 4; ++sub)
#pragma unroll
            for (int r = 0; r < 4; ++r) {
                int key = t0 + sub * 16 + lg * 4 + r;
                if (key > qg) sc[sub][r] = -1e30f;
            }
    }
    float mx = -1e30f;
#pragma unroll
    for (int sub = 0; sub < 4; ++sub) {
        float a01 = fmaxf(sc[sub][0], sc[sub][1]);
        float a23 = fmaxf(sc[sub][2], sc[sub][3]);
        mx = fmaxf(mx, fmaxf(a01, a23));
    }
    mx = fmaxf(mx, __shfl_xor(mx, 16));
    mx = fmaxf(mx, __shfl_xor(mx, 32));
    if (__ballot(mx > M + 8.f)) {           // defer-max: P bounded by 2^8
        const float Mn = fmaxf(M, mx);
        const float a = __builtin_amdgcn_exp2f(M - Mn);
        M = Mn;
        L *= a;
        float ar[4];
#pragma unroll
        for (int r = 0; r < 4; ++r) ar[r] = __shfl(a, lg * 4 + r);
#pragma unroll
        for (int d = 0; d < 8; ++d) {
            O[d][0] *= ar[0]; O[d][1] *= ar[1]; O[d][2] *= ar[2]; O[d][3] *= ar[3];
        }
    }
    float p[4][4];
    float ps = 0.f;
#pragma unroll
    for (int sub = 0; sub < 4; ++sub) {
#pragma unroll
        for (int r = 0; r < 4; ++r) p[sub][r] = __builtin_amdgcn_exp2f(sc[sub][r] - M);
        ps += (p[sub][0] + p[sub][1]) + (p[sub][2] + p[sub][3]);
    }
    ps += __shfl_xor(ps, 16);
    ps += __shfl_xor(ps, 32);
    L += ps;
    pa[0] = pack_pa(p[0], p[1]);
    pa[1] = pack_pa(p[2], p[3]);
}

__global__ __launch_bounds__(256, 2) void flash_mfma(
        const short* __restrict__ Qb, const short* __restrict__ Kb,
        const short* __restrict__ Vb, const float* __restrict__ gnw,
        const float* __restrict__ lam_p, short* __restrict__ Hob) {
    __shared__ short Ksh[KVB * 128];   // row-major, 16B-group xor-swizzled
    __shared__ short VT[HDD * 72];     // VT[d][key], row stride 72 shorts

    const int tid = threadIdx.x;
    const int w  = tid >> 6;
    const int l  = tid & 63;
    const int lq = l & 15;
    const int lg = l >> 4;

    const int blk = blockIdx.x;
    const int bh  = blk & 31;
    const int g   = blk >> 5;
    const int r4  = g >> 3, gc = g & 7;
    const int bx  = (r4 == 0) ? 31 - gc : (r4 == 1) ? gc
                  : (r4 == 2) ? 23 - gc : 8 + gc;    // per-CU balanced (66 tiles)
    const int b = bh >> 4, h = bh & 15;
    const int s0 = bx * 64;
    const float lam = lam_p[0];

    const int qg = s0 + w * 16 + lq;
    const short* qrow = Qb + ((size_t)(b * SDIM + qg)) * HIDD + h * HDD;
    bf16x8 qf[2][2];
#pragma unroll
    for (int br = 0; br < 2; ++br)
#pragma unroll
        for (int ks = 0; ks < 2; ++ks)
            qf[br][ks] = *(const bf16x8*)(qrow + br * 64 + ks * 32 + lg * 8);

    int kkey[4], kcol[4];
#pragma unroll
    for (int i = 0; i < 4; ++i) {
        kkey[i] = w * 16 + i * 4 + lg;
        kcol[i] = (lq * 8) ^ ((kkey[i] & 7) << 3);
    }
    const int kp = tid & 31, dq = tid >> 5;

    const short* Kbase = Kb + ((size_t)(b * SDIM)) * HIDD + h * HDD;
    const short* Vbase = Vb + ((size_t)(b * SDIM)) * HIDD + h * HDD;

    float M1 = -1e30f, M2 = -1e30f, L1 = 0.f, L2 = 0.f;
    f32x4 O1[8] = {}; f32x4 O2[8] = {};

    const int ntmax = bx + 1;
    const int qmin = s0 + w * 16;

    for (int t = 0; t < ntmax; ++t) {
        const size_t trow = (size_t)t * KVB * HIDD;
        __syncthreads();
#pragma unroll
        for (int i = 0; i < 4; ++i)
            gload_lds16(Kbase + trow + (size_t)kkey[i] * HIDD + kcol[i],
                        &Ksh[w * 2048 + i * 512]);
        {
            const short* v0 = Vbase + trow + (size_t)(2 * kp) * HIDD + dq * 16;
            const short* v1 = v0 + HIDD;
            bf16x8 v00 = *(const bf16x8*)v0;
            bf16x8 v01 = *(const bf16x8*)(v0 + 8);
            bf16x8 v10 = *(const bf16x8*)v1;
            bf16x8 v11 = *(const bf16x8*)(v1 + 8);
#pragma unroll
            for (int j = 0; j < 8; ++j) {
                unsigned ua = (unsigned)(unsigned short)v00[j] |
                              ((unsigned)(unsigned short)v10[j] << 16);
                *(unsigned*)&VT[(dq * 16 + j) * 72 + 2 * kp] = ua;
                unsigned ub = (unsigned)(unsigned short)v01[j] |
                              ((unsigned)(unsigned short)v11[j] << 16);
                *(unsigned*)&VT[(dq * 16 + 8 + j) * 72 + 2 * kp] = ub;
            }
        }
        __syncthreads();

        f32x4 sc1[4] = {}; f32x4 sc2[4] = {};
        const int rsw = (lq & 7) << 3;
        __builtin_amdgcn_s_setprio(1);
#pragma unroll
        for (int sub = 0; sub < 4; ++sub) {
            const int rbase = (sub * 16 + lq) * 128;
            bf16x8 k00 = *(const bf16x8*)&Ksh[rbase + ((lg * 8) ^ rsw)];
            bf16x8 k01 = *(const bf16x8*)&Ksh[rbase + ((32 + lg * 8) ^ rsw)];
            bf16x8 k10 = *(const bf16x8*)&Ksh[rbase + ((64 + lg * 8) ^ rsw)];
            bf16x8 k11 = *(const bf16x8*)&Ksh[rbase + ((96 + lg * 8) ^ rsw)];
            sc1[sub] = MFMA16(k00, qf[0][0], sc1[sub]);
            sc1[sub] = MFMA16(k01, qf[0][1], sc1[sub]);
            sc2[sub] = MFMA16(k10, qf[1][0], sc2[sub]);
            sc2[sub] = MFMA16(k11, qf[1][1], sc2[sub]);
        }
        __builtin_amdgcn_s_setprio(0);
        const int t0 = t * KVB;
        const bool domask = (t0 + KVB - 1 > qmin);
        bf16x8 pa1[2], pa2[2];
        softmax_step(sc1, M1, L1, O1, pa1, t0, qg, lg, domask);
        softmax_step(sc2, M2, L2, O2, pa2, t0, qg, lg, domask);

        __builtin_amdgcn_s_setprio(1);
#pragma unroll
        for (int d0 = 0; d0 < 8; ++d0) {
            const short* vrow = &VT[(d0 * 16 + lq) * 72];
            bf16x4 a0 = *(const bf16x4*)&vrow[lg * 4];
            bf16x4 a1 = *(const bf16x4*)&vrow[16 + lg * 4];
            bf16x4 b0 = *(const bf16x4*)&vrow[32 + lg * 4];
            bf16x4 b1 = *(const bf16x4*)&vrow[48 + lg * 4];
            bf16x8 vb0 = __builtin_shufflevector(a0, a1, 0, 1, 2, 3, 4, 5, 6, 7);
            bf16x8 vb1 = __builtin_shufflevector(b0, b1, 0, 1, 2, 3, 4, 5, 6, 7);
            O1[d0] = MFMA16(pa1[0], vb0, O1[d0]);
            O1[d0] = MFMA16(pa1[1], vb1, O1[d0]);
            O2[d0] = MFMA16(pa2[0], vb0, O2[d0]);
            O2[d0] = MFMA16(pa2[1], vb1, O2[d0]);
        }
        __builtin_amdgcn_s_setprio(0);
    }

    const float inv1 = 1.f / L1;
    const float inv2 = lam / L2;
    float i1[4], i2[4];
#pragma unroll
    for (int r = 0; r < 4; ++r) {
        i1[r] = __shfl(inv1, lg * 4 + r);
        i2[r] = __shfl(inv2, lg * 4 + r);
    }
    float gn[8];
#pragma unroll
    for (int d = 0; d < 8; ++d) gn[d] = gnw[d * 16 + lq];
    float od[8][4];
    float ss[4] = {0.f, 0.f, 0.f, 0.f};
#pragma unroll
    for (int d = 0; d < 8; ++d)
#pragma unroll
        for (int r = 0; r < 4; ++r) {
            float o = O1[d][r] * i1[r] - O2[d][r] * i2[r];
            od[d][r] = o;
            ss[r] += o * o;
        }
#pragma unroll
    for (int r = 0; r < 4; ++r) {
        ss[r] += __shfl_xor(ss[r], 1);
        ss[r] += __shfl_xor(ss[r], 2);
        ss[r] += __shfl_xor(ss[r], 4);
        ss[r] += __shfl_xor(ss[r], 8);
    }
#pragma unroll
    for (int r = 0; r < 4; ++r) {
        const float scal = rsqrtf(ss[r] * (1.0f / HDD) + EPS_F) * (1.0f - LAMBDA_INIT_F);
        const size_t orow = ((size_t)(b * SDIM + s0 + w * 16 + lg * 4 + r)) * HIDD + h * HDD;
#pragma unroll
        for (int d = 0; d < 8; ++d)
            Hob[orow + d * 16 + lq] = f2bf(od[d][r] * scal * gn[d]);
    }
}

// ----------------------------------------------------------------- launch ---
extern "C" void kernel_launch(void* const* d_in, const int* in_sizes, int n_in,
                              void* d_out, int out_size, void* d_ws, size_t ws_size,
                              hipStream_t stream) {
    const float* q   = (const float*)d_in[0];
    const float* k   = (const float*)d_in[1];
    const float* v   = (const float*)d_in[2];
    const float* Wq  = (const float*)d_in[3];
    const float* Wk  = (const float*)d_in[4];
    const float* Wv  = (const float*)d_in[5];
    const float* Wo  = (const float*)d_in[6];
    const float* lq1 = (const float*)d_in[7];
    const float* lk1 = (const float*)d_in[8];
    const float* lq2 = (const float*)d_in[9];
    const float* lk2 = (const float*)d_in[10];
    const float* gnw = (const float*)d_in[11];
    const float* cosE = (const float*)d_in[12];
    const float* sinE = (const float*)d_in[13];
    float* out = (float*)d_out;

    const size_t TEN = (size_t)BDIM * SDIM * HIDD;  // 8388608 = 2^23
    const int   WN  = HIDD * HIDD;                  // 4194304 = 2^22

    short* wsS = (short*)d_ws;
    short* Qb   = wsS;
    short* Kb   = wsS + TEN;
    short* Vb   = wsS + 2 * TEN;
    short* xqkv = wsS + 3 * TEN;
    short* wb4  = wsS + 6 * TEN;
    float* lamp = (float*)(wsS + 6 * TEN + (size_t)4 * WN);
    short* Hob  = xqkv;

    conv_all<<<20481, 256, 0, stream>>>(q, k, v, Wq, Wk, Wv, Wo,
                                        lq1, lk1, lq2, lk2, xqkv, wb4, lamp);

    dim3 gq(HIDD / 128, MTOT / 128, 3);
    qkv_gemm<<<gq, 256, 0, stream>>>(xqkv, xqkv + TEN, xqkv + 2 * TEN, wb4,
                                     Qb, Kb, Vb, cosE, sinE);

    flash_mfma<<<(SDIM / 64) * BDIM * NHH, 256, 0, stream>>>(Qb, Kb, Vb, gnw, lamp, Hob);

    dim3 go(HIDD / 128, MTOT / 128);
    o_gemm<<<go, 256, 0, stream>>>(Hob, wb4 + (size_t)3 * WN, out);
}

// Round 14
// 302.924 us; speedup vs baseline: 1.1178x; 1.0810x over previous
//
#include <hip/hip_runtime.h>
#include <math.h>

#define BDIM 2
#define SDIM 2048
#define HIDD 2048
#define NHH 16
#define HDD 128
#define QKDD 64
#define MTOT (BDIM*SDIM)   // 4096

constexpr float LAMBDA_INIT_F = 0.3555090675909693f;  // 0.8 - 0.6*exp(-0.3)
constexpr float EPS_F = 1e-6f;
constexpr float SCALE2_F = 0.18033688011112042f;      // (1/8) * log2(e)

typedef float f32x4 __attribute__((ext_vector_type(4)));
typedef short bf16x8 __attribute__((ext_vector_type(8)));
typedef short bf16x4 __attribute__((ext_vector_type(4)));

#define MFMA16(a, b, c) __builtin_amdgcn_mfma_f32_16x16x32_bf16((a), (b), (c), 0, 0, 0)

__device__ __forceinline__ short f2bf(float f) {
    unsigned u = __float_as_uint(f);
    u += 0x7FFFu + ((u >> 16) & 1u);   // RNE
    return (short)(u >> 16);
}
__device__ __forceinline__ unsigned pk2(float a, float b) {
    return (unsigned)(unsigned short)f2bf(a) | ((unsigned)(unsigned short)f2bf(b) << 16);
}
// HW packed f32->bf16 (RNE), lo=src0 hi=src1.
__device__ __forceinline__ unsigned cvtpk(float lo, float hi) {
    unsigned r;
    asm("v_cvt_pk_bf16_f32 %0, %1, %2" : "=v"(r) : "v"(lo), "v"(hi));
    return r;
}

__device__ __forceinline__ void gload_lds16(const void* g, void* l) {
    __builtin_amdgcn_global_load_lds(
        (const __attribute__((address_space(1))) void*)g,
        (__attribute__((address_space(3))) void*)l, 16, 0, 0);
}
__device__ __forceinline__ void waitv8() { asm volatile("s_waitcnt vmcnt(8)" ::: "memory"); }
__device__ __forceinline__ void waitv0() { asm volatile("s_waitcnt vmcnt(0)" ::: "memory"); }
__device__ __forceinline__ void waitl0() { asm volatile("s_waitcnt lgkmcnt(0)" ::: "memory"); }
#define SBAR()   __builtin_amdgcn_s_barrier()
#define SCHEDB() __builtin_amdgcn_sched_barrier(0)

// ---------------------------------------------------------------- lambda ----
__global__ void lambda_kernel(const float* __restrict__ lq1, const float* __restrict__ lk1,
                              const float* __restrict__ lq2, const float* __restrict__ lk2,
                              float* __restrict__ lam_out) {
    int l = threadIdx.x;
    float d1 = lq1[l] * lk1[l] + lq1[l + 64] * lk1[l + 64];
    float d2 = lq2[l] * lk2[l] + lq2[l + 64] * lk2[l + 64];
#pragma unroll
    for (int o = 32; o > 0; o >>= 1) {
        d1 += __shfl_down(d1, o);
        d2 += __shfl_down(d2, o);
    }
    if (l == 0) lam_out[0] = expf(d1) - expf(d2) + LAMBDA_INIT_F;
}

// ---------------------------------------------------------------- convert ---
// Exact-span 1D grid: regions [q|k|v] (2^23 each) then [Wq|Wk|Wv|Wo] (2^22).
// Total 41943040 elements / 2048 per block = 20480 blocks, zero dead blocks.
__global__ __launch_bounds__(256) void conv_all(
        const float* __restrict__ q, const float* __restrict__ k,
        const float* __restrict__ v, const float* __restrict__ Wq,
        const float* __restrict__ Wk, const float* __restrict__ Wv,
        const float* __restrict__ Wo, short* __restrict__ xdst,
        short* __restrict__ wdst) {
    const size_t TEN_C = (size_t)1 << 23;
    const size_t WN_C  = (size_t)1 << 22;
    size_t i = ((size_t)blockIdx.x * 256 + threadIdx.x) * 8;
    const float* src;
    short* dst;
    size_t off;
    if (i < 3 * TEN_C) {
        int y = (int)(i >> 23);
        off = i & (TEN_C - 1);
        src = (y == 0) ? q : (y == 1) ? k : v;
        dst = xdst + ((size_t)y << 23);
    } else {
        size_t j = i - 3 * TEN_C;
        int y = (int)(j >> 22);
        off = j & (WN_C - 1);
        src = (y == 0) ? Wq : (y == 1) ? Wk : (y == 2) ? Wv : Wo;
        dst = wdst + ((size_t)y << 22);
    }
    float4 a = *(const float4*)&src[off];
    float4 b = *(const float4*)&src[off + 4];
    uint4 o;
    o.x = pk2(a.x, a.y); o.y = pk2(a.z, a.w);
    o.z = pk2(b.x, b.y); o.w = pk2(b.z, b.w);
    *(uint4*)&dst[off] = o;
}

// ------------------------------------------------------------ bf16 GEMM -----
// C[M,N] = X[M,K](bf16) @ W[N,K]^T(bf16). 128x128 tile, BK=64, 4 waves (2x2).
// Double-buffered LDS + counted vmcnt pipeline (round-7 validated).
#define GK 2048

__device__ __forceinline__ void gemm_mainloop(
        const short* __restrict__ X, const short* __restrict__ W,
        short* As, short* Bs, f32x4 acc[4][4],
        int bm, int bn, int w, int l, int lq, int lg, int wr, int wc) {
    const int scol = (((l & 7) ^ (l >> 3)) << 3);
    const int rsw  = (lq & 7) << 3;
    const short* aS[4]; const short* bS[4];
#pragma unroll
    for (int i = 0; i < 4; ++i) {
        const int c = w * 4 + i;
        aS[i] = X + (size_t)(bm + c * 8 + (l >> 3)) * GK + scol;
        bS[i] = W + (size_t)(bn + c * 8 + (l >> 3)) * GK + scol;
    }
    const int dOff = (w * 4) * 512;

#pragma unroll
    for (int i = 0; i < 4; ++i) {
        gload_lds16(aS[i], As + dOff + i * 512);
        gload_lds16(bS[i], Bs + dOff + i * 512);
    }
#pragma unroll
    for (int i = 0; i < 4; ++i) {
        gload_lds16(aS[i] + 64, As + 8192 + dOff + i * 512);
        gload_lds16(bS[i] + 64, Bs + 8192 + dOff + i * 512);
    }
    waitv8();
    SBAR();

    for (int t = 0; t < 30; ++t) {
        const short* Ab = As + (t & 1) * 8192;
        const short* Bb = Bs + (t & 1) * 8192;
        bf16x8 a[4][2], b[4][2];
#pragma unroll
        for (int m = 0; m < 4; ++m)
#pragma unroll
            for (int kk = 0; kk < 2; ++kk)
                a[m][kk] = *(const bf16x8*)&Ab[(wr * 64 + m * 16 + lq) * 64 + ((kk * 32 + lg * 8) ^ rsw)];
#pragma unroll
        for (int n = 0; n < 4; ++n)
#pragma unroll
            for (int kk = 0; kk < 2; ++kk)
                b[n][kk] = *(const bf16x8*)&Bb[(wc * 64 + n * 16 + lq) * 64 + ((kk * 32 + lg * 8) ^ rsw)];
        waitl0(); SCHEDB();
        SBAR();
        {
            short* Ad = As + (t & 1) * 8192 + dOff;
            short* Bd = Bs + (t & 1) * 8192 + dOff;
#pragma unroll
            for (int i = 0; i < 4; ++i) {
                gload_lds16(aS[i] + (t + 2) * 64, Ad + i * 512);
                gload_lds16(bS[i] + (t + 2) * 64, Bd + i * 512);
            }
        }
        SCHEDB();
#pragma unroll
        for (int kk = 0; kk < 2; ++kk)
#pragma unroll
            for (int m = 0; m < 4; ++m)
#pragma unroll
                for (int n = 0; n < 4; ++n)
                    acc[m][n] = MFMA16(a[m][kk], b[n][kk], acc[m][n]);
        waitv8();
        SBAR();
    }
    {
        bf16x8 a[4][2], b[4][2];
#pragma unroll
        for (int m = 0; m < 4; ++m)
#pragma unroll
            for (int kk = 0; kk < 2; ++kk)
                a[m][kk] = *(const bf16x8*)&As[(wr * 64 + m * 16 + lq) * 64 + ((kk * 32 + lg * 8) ^ rsw)];
#pragma unroll
        for (int n = 0; n < 4; ++n)
#pragma unroll
            for (int kk = 0; kk < 2; ++kk)
                b[n][kk] = *(const bf16x8*)&Bs[(wc * 64 + n * 16 + lq) * 64 + ((kk * 32 + lg * 8) ^ rsw)];
        waitl0(); SCHEDB();
        SBAR();
#pragma unroll
        for (int kk = 0; kk < 2; ++kk)
#pragma unroll
            for (int m = 0; m < 4; ++m)
#pragma unroll
                for (int n = 0; n < 4; ++n)
                    acc[m][n] = MFMA16(a[m][kk], b[n][kk], acc[m][n]);
        waitv0();
        SBAR();
    }
    {
        bf16x8 a[4][2], b[4][2];
#pragma unroll
        for (int m = 0; m < 4; ++m)
#pragma unroll
            for (int kk = 0; kk < 2; ++kk)
                a[m][kk] = *(const bf16x8*)&As[8192 + (wr * 64 + m * 16 + lq) * 64 + ((kk * 32 + lg * 8) ^ rsw)];
#pragma unroll
        for (int n = 0; n < 4; ++n)
#pragma unroll
            for (int kk = 0; kk < 2; ++kk)
                b[n][kk] = *(const bf16x8*)&Bs[8192 + (wc * 64 + n * 16 + lq) * 64 + ((kk * 32 + lg * 8) ^ rsw)];
#pragma unroll
        for (int kk = 0; kk < 2; ++kk)
#pragma unroll
            for (int m = 0; m < 4; ++m)
#pragma unroll
                for (int n = 0; n < 4; ++n)
                    acc[m][n] = MFMA16(a[m][kk], b[n][kk], acc[m][n]);
    }
}

// Batched QKV projection: z=0 -> Q (RoPE), z=1 -> K (RoPE), z=2 -> V (plain).
__global__ __launch_bounds__(256) void qkv_gemm(
        const short* __restrict__ Xq, const short* __restrict__ Xk, const short* __restrict__ Xv,
        const short* __restrict__ Wb, short* __restrict__ Qb, short* __restrict__ Kb,
        short* __restrict__ Vb, const float* __restrict__ cosE, const float* __restrict__ sinE) {
    __shared__ short As[2 * 128 * 64];
    __shared__ short Bs[2 * 128 * 64];
    const int tid = threadIdx.x;
    const int w = tid >> 6, l = tid & 63;
    const int lq = l & 15, lg = l >> 4;
    const int wr = w >> 1, wc = w & 1;
    const int bm = blockIdx.y * 128;
    const int bn = blockIdx.x * 128;
    const int z  = blockIdx.z;

    const short* X = (z == 0) ? Xq : (z == 1) ? Xk : Xv;
    const short* W = Wb + (size_t)z * HIDD * HIDD;
    short* Cb      = (z == 0) ? Qb : (z == 1) ? Kb : Vb;

    f32x4 acc[4][4] = {};
    gemm_mainloop(X, W, As, Bs, acc, bm, bn, w, l, lq, lg, wr, wc);

    const bool dorope = (z < 2);
#pragma unroll
    for (int m = 0; m < 4; ++m)
#pragma unroll
        for (int n = 0; n < 4; ++n) {
            const int row0 = bm + wr * 64 + m * 16 + lg * 4;
            const int col  = bn + wc * 64 + n * 16 + lq;
#pragma unroll
            for (int r = 0; r < 4; ++r) {
                float vv = acc[m][n][r];
                if (dorope) {
                    const int s  = (row0 + r) & (SDIM - 1);
                    const int c6 = col & 63;
                    const float cv = cosE[s * HDD + c6];
                    const float sv = sinE[s * HDD + c6];
                    const float p = __shfl_xor(vv, 1);
                    vv = (col & 1) ? vv * cv + p * sv : vv * cv - p * sv;
                }
                Cb[(size_t)(row0 + r) * HIDD + col] = f2bf(vv);
            }
        }
}

// Output projection: fp32 C.
__global__ __launch_bounds__(256) void o_gemm(const short* __restrict__ Ab,
                                              const short* __restrict__ Bb,
                                              float* __restrict__ C) {
    __shared__ short As[2 * 128 * 64];
    __shared__ short Bs[2 * 128 * 64];
    const int tid = threadIdx.x;
    const int w = tid >> 6, l = tid & 63;
    const int lq = l & 15, lg = l >> 4;
    const int wr = w >> 1, wc = w & 1;
    const int bm = blockIdx.y * 128;
    const int bn = blockIdx.x * 128;

    f32x4 acc[4][4] = {};
    gemm_mainloop(Ab, Bb, As, Bs, acc, bm, bn, w, l, lq, lg, wr, wc);

#pragma unroll
    for (int m = 0; m < 4; ++m)
#pragma unroll
        for (int n = 0; n < 4; ++n) {
            const int row0 = bm + wr * 64 + m * 16 + lg * 4;
            const int col  = bn + wc * 64 + n * 16 + lq;
#pragma unroll
            for (int r = 0; r < 4; ++r)
                C[(size_t)(row0 + r) * HIDD + col] = acc[m][n][r];
        }
}

// ------------------------------------------------- MFMA differential flash --
// Round-7 validated structure + CU load-balance bx permutation + cvt_pk P-pack.
// Balance: assuming sequential block->CU assignment (c, c+256, c+512, c+768),
// rows r=g>>3 map bx as {31-gc, gc, 23-gc, 8+gc} -> every CU sums to 66 tiles.
#define KVB 64

__device__ __forceinline__ bf16x8 pack_pa(const float p0[4], const float p1[4]) {
    union { unsigned u[4]; bf16x8 v; } r;
    r.u[0] = cvtpk(p0[0], p0[1]);
    r.u[1] = cvtpk(p0[2], p0[3]);
    r.u[2] = cvtpk(p1[0], p1[1]);
    r.u[3] = cvtpk(p1[2], p1[3]);
    return r.v;
}

__device__ __forceinline__ void softmax_step(
        f32x4 sc[4], float& M, float& L, f32x4 O[8], bf16x8 pa[2],
        int t0, int qg, int lg, bool domask) {
    // scores -> base-2 domain: s2 = (S / sqrt(64)) * log2(e)
#pragma unroll
    for (int sub = 0; sub < 4; ++sub)
#pragma unroll
        for (int r = 0; r < 4; ++r) {
            float s = sc[sub][r] * SCALE2_F;
            if (domask) {
                int key = t0 + sub * 16 + lg * 4 + r;
                s = (key <= qg) ? s : -1e30f;
            }
            sc[sub][r] = s;
        }
    float mx = -1e30f;
#pragma unroll
    for (int sub = 0; sub < 4; ++sub) {
        float a01 = fmaxf(sc[sub][0], sc[sub][1]);
        float a23 = fmaxf(sc[sub][2], sc[sub][3]);
        mx = fmaxf(mx, fmaxf(a01, a23));
    }
    mx = fmaxf(mx, __shfl_xor(mx, 16));
    mx = fmaxf(mx, __shfl_xor(mx, 32));
    if (__ballot(mx > M + 8.f)) {           // defer-max: P bounded by 2^8
        const float Mn = fmaxf(M, mx);
        const float a = __builtin_amdgcn_exp2f(M - Mn);
        M = Mn;
        L *= a;
        float ar[4];
#pragma unroll
        for (int r = 0; r < 4; ++r) ar[r] = __shfl(a, lg * 4 + r);
#pragma unroll
        for (int d = 0; d < 8; ++d) {
            O[d][0] *= ar[0]; O[d][1] *= ar[1]; O[d][2] *= ar[2]; O[d][3] *= ar[3];
        }
    }
    float p[4][4];
    float ps = 0.f;
#pragma unroll
    for (int sub = 0; sub < 4; ++sub) {
#pragma unroll
        for (int r = 0; r < 4; ++r) p[sub][r] = __builtin_amdgcn_exp2f(sc[sub][r] - M);
        ps += (p[sub][0] + p[sub][1]) + (p[sub][2] + p[sub][3]);
    }
    ps += __shfl_xor(ps, 16);
    ps += __shfl_xor(ps, 32);
    L += ps;
    pa[0] = pack_pa(p[0], p[1]);
    pa[1] = pack_pa(p[2], p[3]);
}

__global__ __launch_bounds__(256, 2) void flash_mfma(
        const short* __restrict__ Qb, const short* __restrict__ Kb,
        const short* __restrict__ Vb, const float* __restrict__ gnw,
        const float* __restrict__ lam_p, short* __restrict__ Hob) {
    __shared__ short Ksh[KVB * 128];   // row-major, 16B-group xor-swizzled
    __shared__ short VT[HDD * 72];     // VT[d][key], row stride 72 shorts

    const int tid = threadIdx.x;
    const int w  = tid >> 6;
    const int l  = tid & 63;
    const int lq = l & 15;
    const int lg = l >> 4;

    const int blk = blockIdx.x;
    const int bh  = blk & 31;
    const int g   = blk >> 5;
    const int r4  = g >> 3, gc = g & 7;
    const int bx  = (r4 == 0) ? 31 - gc : (r4 == 1) ? gc
                  : (r4 == 2) ? 23 - gc : 8 + gc;    // per-CU balanced
    const int b = bh >> 4, h = bh & 15;
    const int s0 = bx * 64;
    const float lam = lam_p[0];

    const int qg = s0 + w * 16 + lq;
    const short* qrow = Qb + ((size_t)(b * SDIM + qg)) * HIDD + h * HDD;
    bf16x8 qf[2][2];
#pragma unroll
    for (int br = 0; br < 2; ++br)
#pragma unroll
        for (int ks = 0; ks < 2; ++ks)
            qf[br][ks] = *(const bf16x8*)(qrow + br * 64 + ks * 32 + lg * 8);

    int kkey[4], kcol[4];
#pragma unroll
    for (int i = 0; i < 4; ++i) {
        kkey[i] = w * 16 + i * 4 + lg;
        kcol[i] = (lq * 8) ^ ((kkey[i] & 7) << 3);
    }
    const int kp = tid & 31, dq = tid >> 5;

    const short* Kbase = Kb + ((size_t)(b * SDIM)) * HIDD + h * HDD;
    const short* Vbase = Vb + ((size_t)(b * SDIM)) * HIDD + h * HDD;

    float M1 = -1e30f, M2 = -1e30f, L1 = 0.f, L2 = 0.f;
    f32x4 O1[8] = {}; f32x4 O2[8] = {};

    const int ntmax = bx + 1;
    const int qmin = s0 + w * 16;

    for (int t = 0; t < ntmax; ++t) {
        const size_t trow = (size_t)t * KVB * HIDD;
        __syncthreads();
#pragma unroll
        for (int i = 0; i < 4; ++i)
            gload_lds16(Kbase + trow + (size_t)kkey[i] * HIDD + kcol[i],
                        &Ksh[w * 2048 + i * 512]);
        {
            const short* v0 = Vbase + trow + (size_t)(2 * kp) * HIDD + dq * 16;
            const short* v1 = v0 + HIDD;
            bf16x8 v00 = *(const bf16x8*)v0;
            bf16x8 v01 = *(const bf16x8*)(v0 + 8);
            bf16x8 v10 = *(const bf16x8*)v1;
            bf16x8 v11 = *(const bf16x8*)(v1 + 8);
#pragma unroll
            for (int j = 0; j < 8; ++j) {
                unsigned ua = (unsigned)(unsigned short)v00[j] |
                              ((unsigned)(unsigned short)v10[j] << 16);
                *(unsigned*)&VT[(dq * 16 + j) * 72 + 2 * kp] = ua;
                unsigned ub = (unsigned)(unsigned short)v01[j] |
                              ((unsigned)(unsigned short)v11[j] << 16);
                *(unsigned*)&VT[(dq * 16 + 8 + j) * 72 + 2 * kp] = ub;
            }
        }
        __syncthreads();

        f32x4 sc1[4] = {}; f32x4 sc2[4] = {};
        const int rsw = (lq & 7) << 3;
        __builtin_amdgcn_s_setprio(1);
#pragma unroll
        for (int sub = 0; sub < 4; ++sub) {
            const int rbase = (sub * 16 + lq) * 128;
            bf16x8 k00 = *(const bf16x8*)&Ksh[rbase + ((lg * 8) ^ rsw)];
            bf16x8 k01 = *(const bf16x8*)&Ksh[rbase + ((32 + lg * 8) ^ rsw)];
            bf16x8 k10 = *(const bf16x8*)&Ksh[rbase + ((64 + lg * 8) ^ rsw)];
            bf16x8 k11 = *(const bf16x8*)&Ksh[rbase + ((96 + lg * 8) ^ rsw)];
            sc1[sub] = MFMA16(k00, qf[0][0], sc1[sub]);
            sc1[sub] = MFMA16(k01, qf[0][1], sc1[sub]);
            sc2[sub] = MFMA16(k10, qf[1][0], sc2[sub]);
            sc2[sub] = MFMA16(k11, qf[1][1], sc2[sub]);
        }
        __builtin_amdgcn_s_setprio(0);
        const int t0 = t * KVB;
        const bool domask = (t0 + KVB - 1 > qmin);
        bf16x8 pa1[2], pa2[2];
        softmax_step(sc1, M1, L1, O1, pa1, t0, qg, lg, domask);
        softmax_step(sc2, M2, L2, O2, pa2, t0, qg, lg, domask);

        __builtin_amdgcn_s_setprio(1);
#pragma unroll
        for (int d0 = 0; d0 < 8; ++d0) {
            const short* vrow = &VT[(d0 * 16 + lq) * 72];
            bf16x4 a0 = *(const bf16x4*)&vrow[lg * 4];
            bf16x4 a1 = *(const bf16x4*)&vrow[16 + lg * 4];
            bf16x4 b0 = *(const bf16x4*)&vrow[32 + lg * 4];
            bf16x4 b1 = *(const bf16x4*)&vrow[48 + lg * 4];
            bf16x8 vb0 = __builtin_shufflevector(a0, a1, 0, 1, 2, 3, 4, 5, 6, 7);
            bf16x8 vb1 = __builtin_shufflevector(b0, b1, 0, 1, 2, 3, 4, 5, 6, 7);
            O1[d0] = MFMA16(pa1[0], vb0, O1[d0]);
            O1[d0] = MFMA16(pa1[1], vb1, O1[d0]);
            O2[d0] = MFMA16(pa2[0], vb0, O2[d0]);
            O2[d0] = MFMA16(pa2[1], vb1, O2[d0]);
        }
        __builtin_amdgcn_s_setprio(0);
    }

    const float inv1 = 1.f / L1;
    const float inv2 = lam / L2;
    float i1[4], i2[4];
#pragma unroll
    for (int r = 0; r < 4; ++r) {
        i1[r] = __shfl(inv1, lg * 4 + r);
        i2[r] = __shfl(inv2, lg * 4 + r);
    }
    float gn[8];
#pragma unroll
    for (int d = 0; d < 8; ++d) gn[d] = gnw[d * 16 + lq];
    float od[8][4];
    float ss[4] = {0.f, 0.f, 0.f, 0.f};
#pragma unroll
    for (int d = 0; d < 8; ++d)
#pragma unroll
        for (int r = 0; r < 4; ++r) {
            float o = O1[d][r] * i1[r] - O2[d][r] * i2[r];
            od[d][r] = o;
            ss[r] += o * o;
        }
#pragma unroll
    for (int r = 0; r < 4; ++r) {
        ss[r] += __shfl_xor(ss[r], 1);
        ss[r] += __shfl_xor(ss[r], 2);
        ss[r] += __shfl_xor(ss[r], 4);
        ss[r] += __shfl_xor(ss[r], 8);
    }
#pragma unroll
    for (int r = 0; r < 4; ++r) {
        const float scal = rsqrtf(ss[r] * (1.0f / HDD) + EPS_F) * (1.0f - LAMBDA_INIT_F);
        const size_t orow = ((size_t)(b * SDIM + s0 + w * 16 + lg * 4 + r)) * HIDD + h * HDD;
#pragma unroll
        for (int d = 0; d < 8; ++d)
            Hob[orow + d * 16 + lq] = f2bf(od[d][r] * scal * gn[d]);
    }
}

// ----------------------------------------------------------------- launch ---
extern "C" void kernel_launch(void* const* d_in, const int* in_sizes, int n_in,
                              void* d_out, int out_size, void* d_ws, size_t ws_size,
                              hipStream_t stream) {
    const float* q   = (const float*)d_in[0];
    const float* k   = (const float*)d_in[1];
    const float* v   = (const float*)d_in[2];
    const float* Wq  = (const float*)d_in[3];
    const float* Wk  = (const float*)d_in[4];
    const float* Wv  = (const float*)d_in[5];
    const float* Wo  = (const float*)d_in[6];
    const float* lq1 = (const float*)d_in[7];
    const float* lk1 = (const float*)d_in[8];
    const float* lq2 = (const float*)d_in[9];
    const float* lk2 = (const float*)d_in[10];
    const float* gnw = (const float*)d_in[11];
    const float* cosE = (const float*)d_in[12];
    const float* sinE = (const float*)d_in[13];
    float* out = (float*)d_out;

    const size_t TEN = (size_t)BDIM * SDIM * HIDD;  // 8388608 = 2^23
    const int   WN  = HIDD * HIDD;                  // 4194304 = 2^22

    short* wsS = (short*)d_ws;
    short* Qb   = wsS;
    short* Kb   = wsS + TEN;
    short* Vb   = wsS + 2 * TEN;
    short* xqkv = wsS + 3 * TEN;
    short* wb4  = wsS + 6 * TEN;
    float* lamp = (float*)(wsS + 6 * TEN + (size_t)4 * WN);
    short* Hob  = xqkv;

    lambda_kernel<<<1, 64, 0, stream>>>(lq1, lk1, lq2, lk2, lamp);

    conv_all<<<20480, 256, 0, stream>>>(q, k, v, Wq, Wk, Wv, Wo, xqkv, wb4);

    dim3 gq(HIDD / 128, MTOT / 128, 3);
    qkv_gemm<<<gq, 256, 0, stream>>>(xqkv, xqkv + TEN, xqkv + 2 * TEN, wb4,
                                     Qb, Kb, Vb, cosE, sinE);

    flash_mfma<<<(SDIM / 64) * BDIM * NHH, 256, 0, stream>>>(Qb, Kb, Vb, gnw, lamp, Hob);

    dim3 go(HIDD / 128, MTOT / 128);
    o_gemm<<<go, 256, 0, stream>>>(Hob, wb4 + (size_t)3 * WN, out);
}